// Round 2
// baseline (13167.421 us; speedup 1.0000x reference)
//
#include <hip/hip_runtime.h>
#include <cstdint>
#include <cstddef>

#define B_    256
#define T_    1024
#define NDYN  20
#define DH    64
#define DZ    128
#define HIDN  64
#define GCOLS 384   // 3*DZ
#define XDIM  104   // 2*NDYN + DH

// chunk-padded LDS index: 16-float chunks at stride 20 (conflict-free float4 reads)
__device__ __forceinline__ int cpad(int k) { return (k >> 4) * 20 + (k & 15); }

// DPP cross-lane add (VALU pipe, not LDS). CTRL: 0xB1=quad_perm(1,0,3,2) ~ xor1,
// 0x4E=quad_perm(2,3,0,1) ~ xor2, 0x141=row_half_mirror ~ xor4 (valid once quads uniform).
template<int CTRL, int XORMASK>
__device__ __forceinline__ float dpp_sum(float v) {
#if __has_builtin(__builtin_amdgcn_mov_dpp)
  int o = __builtin_amdgcn_mov_dpp(__float_as_int(v), CTRL, 0xF, 0xF, true);
  return v + __int_as_float(o);
#else
  return v + __shfl_xor(v, XORMASK);
#endif
}

__device__ __forceinline__ float tanh_fast(float x) {
  float a = __expf(-2.f * fabsf(x));
  return copysignf((1.f - a) / (1.f + a), x);
}
__device__ __forceinline__ float sigm(float x) { return 1.f / (1.f + __expf(-x)); }

__global__ __launch_bounds__(384, 2) void odernn_kernel(
    const float* __restrict__ z0, const float* __restrict__ tdyn,
    const float* __restrict__ Y, const float* __restrict__ Mm,
    const float* __restrict__ Hh, const int* __restrict__ lens,
    const float* __restrict__ W0, const float* __restrict__ b0,
    const float* __restrict__ W1, const float* __restrict__ b1,
    const float* __restrict__ W2, const float* __restrict__ b2,
    const float* __restrict__ Wih, const float* __restrict__ bih,
    const float* __restrict__ Whh, const float* __restrict__ bhh,
    const float* __restrict__ gi_pre, float* __restrict__ out, int use_gi)
{
  const int tid = threadIdx.x;
  const int b   = blockIdx.x;

  __shared__ __align__(16) float vinP[160];   // RK4 input v, 8 chunks of 16 @ stride 20
  __shared__ __align__(16) float h1P[80];     // 4 chunks
  __shared__ __align__(16) float h2P[80];     // 4 chunks
  __shared__ __align__(16) float zodeL[128];  // flat, float4-broadcast in GRU
  __shared__ float zcurL[128];
  __shared__ float gateL[384];
  __shared__ float gateN[128];
  __shared__ float xsL[112];
  __shared__ float tprevL;

  // Register-resident weights (all fp32):
  //   whh[128]: GRU column tid of Whh
  //   wA[32]: tid<256 -> L0 slice ; tid>=256 -> L2 slice
  //   wB[32]: tid<128 -> L1 slice ; 128<=tid<256 -> L2 slice
  float wA[32], wB[32], whh[128];

  #pragma unroll
  for (int i = 0; i < 128; ++i) whh[i] = Whh[i * GCOLS + tid];

  if (tid < 256) {            // L0: jg=tid>>3 (2 outputs), p=tid&7 (K-chunk of 16)
    const int jg = tid >> 3, p = tid & 7, j0 = 2 * jg, kb = 16 * p;
    #pragma unroll
    for (int i = 0; i < 16; ++i) {
      wA[i]      = W0[(kb + i) * HIDN + j0];
      wA[16 + i] = W0[(kb + i) * HIDN + j0 + 1];
    }
  } else {                    // L2 (upper half of thread slots)
    const int u = tid - 128, jg = u >> 2, p = u & 3, j0 = 2 * jg, kb = 16 * p;
    #pragma unroll
    for (int i = 0; i < 16; ++i) {
      wA[i]      = W2[(kb + i) * DZ + j0];
      wA[16 + i] = W2[(kb + i) * DZ + j0 + 1];
    }
  }
  if (tid < 128) {            // L1: jg=tid>>2, p=tid&3
    const int jg = tid >> 2, p = tid & 3, j0 = 2 * jg, kb = 16 * p;
    #pragma unroll
    for (int i = 0; i < 16; ++i) {
      wB[i]      = W1[(kb + i) * HIDN + j0];
      wB[16 + i] = W1[(kb + i) * HIDN + j0 + 1];
    }
  } else if (tid < 256) {     // L2 (lower half of thread slots)
    const int u = tid - 128, jg = u >> 2, p = u & 3, j0 = 2 * jg, kb = 16 * p;
    #pragma unroll
    for (int i = 0; i < 16; ++i) {
      wB[i]      = W2[(kb + i) * DZ + j0];
      wB[16 + i] = W2[(kb + i) * DZ + j0 + 1];
    }
  }

  float b0r = 0.f, b1r = 0.f, b2r = 0.f;
  if (tid < 256 && (tid & 7) < 2) b0r = b0[2 * (tid >> 3) + (tid & 7)];
  if (tid < 128 && (tid & 3) < 2) b1r = b1[2 * (tid >> 2) + (tid & 3)];
  if (tid >= 128 && ((tid - 128) & 3) < 2)
    b2r = b2[2 * ((tid - 128) >> 2) + ((tid - 128) & 3)];
  const float bhhr = bhh[tid];
  const float bihr = bih[tid];
  const int   lenb = lens[b];

  if (tid < 128) {
    float zv = z0[(size_t)b * DZ + tid];
    vinP[cpad(tid)] = zv;
    zcurL[tid] = zv;
  }
  if (tid == 0) tprevL = tdyn[(size_t)b * T_];
  __syncthreads();

  float* Zbase = out + (size_t)B_ * DZ;

  const int u2 = tid - 128, jg2 = u2 >> 2, p2 = u2 & 3;  // L2 role (valid tid>=128)
  const int j2 = 2 * jg2 + p2;                           // L2 writer output (p2<2)

  for (int t = 0; t < T_; ++t) {
    const size_t bt = (size_t)b * T_ + t;
    const float tk = tdyn[bt];
    const float dt = fmaxf(tk - tprevL, 0.f);

    float gival = 0.f;
    if (use_gi) {
      gival = gi_pre[bt * GCOLS + tid];   // prefetch; consumed ~500 cyc later
    } else if (tid < XDIM) {
      float v;
      if (tid < 20)      v = Y[bt * NDYN + tid];
      else if (tid < 40) v = Mm[bt * NDYN + (tid - 20)];
      else               v = Hh[bt * DH + (tid - 40)];
      xsL[tid] = v;
    }

    float zreg = 0.f, kacc = 0.f;
    if (tid >= 128 && p2 < 2) zreg = zcurL[j2];

    #pragma unroll
    for (int e = 0; e < 4; ++e) {
      // ---- L0: 64 outs, K=128 ---- (threads 0..255, group of 8, 2 outs each)
      if (tid < 256) {
        const int p = tid & 7, jg = tid >> 3;
        const float4* vp = (const float4*)&vinP[p * 20];
        float a0 = 0.f, a1 = 0.f;
        #pragma unroll
        for (int q = 0; q < 4; ++q) {
          float4 v = vp[q];
          a0 += wA[4*q+0]*v.x + wA[4*q+1]*v.y + wA[4*q+2]*v.z + wA[4*q+3]*v.w;
          a1 += wA[16+4*q+0]*v.x + wA[16+4*q+1]*v.y + wA[16+4*q+2]*v.z + wA[16+4*q+3]*v.w;
        }
        a0 = dpp_sum<0xB1,1>(a0); a0 = dpp_sum<0x4E,2>(a0); a0 = dpp_sum<0x141,4>(a0);
        a1 = dpp_sum<0xB1,1>(a1); a1 = dpp_sum<0x4E,2>(a1); a1 = dpp_sum<0x141,4>(a1);
        if (p < 2)
          h1P[cpad(2 * jg + p)] = tanh_fast((p ? a1 : a0) + b0r);
      }
      __syncthreads();
      // ---- L1: 64 outs, K=64 ---- (threads 0..127, group of 4)
      if (tid < 128) {
        const int p = tid & 3, jg = tid >> 2;
        const float4* hp = (const float4*)&h1P[p * 20];
        float a0 = 0.f, a1 = 0.f;
        #pragma unroll
        for (int q = 0; q < 4; ++q) {
          float4 v = hp[q];
          a0 += wB[4*q+0]*v.x + wB[4*q+1]*v.y + wB[4*q+2]*v.z + wB[4*q+3]*v.w;
          a1 += wB[16+4*q+0]*v.x + wB[16+4*q+1]*v.y + wB[16+4*q+2]*v.z + wB[16+4*q+3]*v.w;
        }
        a0 = dpp_sum<0xB1,1>(a0); a0 = dpp_sum<0x4E,2>(a0);
        a1 = dpp_sum<0xB1,1>(a1); a1 = dpp_sum<0x4E,2>(a1);
        if (p < 2)
          h2P[cpad(2 * jg + p)] = tanh_fast((p ? a1 : a0) + b1r);
      }
      __syncthreads();
      // ---- L2: 128 outs, K=64 ---- (threads 128..383, group of 4)
      if (tid >= 128) {
        const float4* hp = (const float4*)&h2P[p2 * 20];
        float a0 = 0.f, a1 = 0.f;
        if (tid < 256) {
          #pragma unroll
          for (int q = 0; q < 4; ++q) {
            float4 v = hp[q];
            a0 += wB[4*q+0]*v.x + wB[4*q+1]*v.y + wB[4*q+2]*v.z + wB[4*q+3]*v.w;
            a1 += wB[16+4*q+0]*v.x + wB[16+4*q+1]*v.y + wB[16+4*q+2]*v.z + wB[16+4*q+3]*v.w;
          }
        } else {
          #pragma unroll
          for (int q = 0; q < 4; ++q) {
            float4 v = hp[q];
            a0 += wA[4*q+0]*v.x + wA[4*q+1]*v.y + wA[4*q+2]*v.z + wA[4*q+3]*v.w;
            a1 += wA[16+4*q+0]*v.x + wA[16+4*q+1]*v.y + wA[16+4*q+2]*v.z + wA[16+4*q+3]*v.w;
          }
        }
        a0 = dpp_sum<0xB1,1>(a0); a0 = dpp_sum<0x4E,2>(a0);
        a1 = dpp_sum<0xB1,1>(a1); a1 = dpp_sum<0x4E,2>(a1);
        if (p2 < 2) {
          const float kv = dt * ((p2 ? a1 : a0) + b2r);
          if (e == 0)      kacc = kv;
          else if (e == 3) kacc += kv;
          else             kacc += 2.f * kv;
          if (e < 3) {
            const float a = (e == 2) ? 1.f : 0.5f;
            vinP[cpad(j2)] = zreg + a * kv;
          } else {
            zodeL[j2] = zreg + kacc * (1.f / 6.f);
          }
        }
      }
      __syncthreads();
    }

    // ---- GRU: column tid ----
    {
      float gh = bhhr;
      const float4* zp = (const float4*)zodeL;
      #pragma unroll
      for (int q = 0; q < 32; ++q) {
        float4 zv = zp[q];
        gh += whh[4*q+0]*zv.x + whh[4*q+1]*zv.y + whh[4*q+2]*zv.z + whh[4*q+3]*zv.w;
      }
      float gi;
      if (use_gi) gi = gival;
      else {
        gi = bihr;
        for (int i = 0; i < XDIM; ++i) gi += xsL[i] * Wih[(size_t)i * GCOLS + tid];
      }
      if (tid < 256) gateL[tid] = gi + gh;
      else { gateL[tid] = gh; gateN[tid - 256] = gi; }
    }
    __syncthreads();

    if (tid < 128) {
      const float r  = sigm(gateL[tid]);
      const float uu = sigm(gateL[128 + tid]);
      const float n  = tanh_fast(gateN[tid] + r * gateL[256 + tid]);
      const float zo = zodeL[tid];
      const float zn = (1.f - uu) * n + uu * zo;
      const float znew = (t < lenb) ? zn : zo;
      vinP[cpad(tid)] = znew;
      zcurL[tid] = znew;
      Zbase[bt * DZ + tid] = znew;
    }
    if (tid == 0) tprevL = tk;
    __syncthreads();
  }

  if (tid < 128) out[(size_t)b * DZ + tid] = zcurL[tid];
}

// ---- pass 1: gi[bt][c] = b_ih[c] + x[bt] @ W_ih  (input-only, fully parallel, fp32)
__global__ __launch_bounds__(384) void gi_precompute(
    const float* __restrict__ Y, const float* __restrict__ Mm,
    const float* __restrict__ Hh, const float* __restrict__ Wih,
    const float* __restrict__ bih, float* __restrict__ gi)
{
  __shared__ float Xs[XDIM][16];
  const int tid = threadIdx.x;
  const size_t bt0 = (size_t)blockIdx.x * 16;
  for (int idx = tid; idx < XDIM * 16; idx += 384) {
    int r = idx & 15, c = idx >> 4;
    size_t bt = bt0 + r;
    float v;
    if (c < 20)      v = Y[bt * NDYN + c];
    else if (c < 40) v = Mm[bt * NDYN + (c - 20)];
    else             v = Hh[bt * DH + (c - 40)];
    Xs[c][r] = v;
  }
  __syncthreads();
  float acc[16];
  const float bv = bih[tid];
  #pragma unroll
  for (int r = 0; r < 16; ++r) acc[r] = bv;
  for (int i = 0; i < XDIM; ++i) {
    float w = Wih[i * GCOLS + tid];
    const float4* xp = (const float4*)(&Xs[i][0]);
    #pragma unroll
    for (int q = 0; q < 4; ++q) {
      float4 xv = xp[q];
      acc[4*q + 0] += xv.x * w;
      acc[4*q + 1] += xv.y * w;
      acc[4*q + 2] += xv.z * w;
      acc[4*q + 3] += xv.w * w;
    }
  }
  #pragma unroll
  for (int r = 0; r < 16; ++r) gi[(bt0 + r) * GCOLS + tid] = acc[r];
}

extern "C" void kernel_launch(void* const* d_in, const int* in_sizes, int n_in,
                              void* d_out, int out_size, void* d_ws, size_t ws_size,
                              hipStream_t stream) {
  const float* z0   = (const float*)d_in[0];
  const float* tdyn = (const float*)d_in[1];
  const float* Y    = (const float*)d_in[2];
  const float* Mm   = (const float*)d_in[3];
  const float* Hh   = (const float*)d_in[4];
  const int*   lens = (const int*)d_in[5];
  const float* W0   = (const float*)d_in[6];
  const float* b0   = (const float*)d_in[7];
  const float* W1   = (const float*)d_in[8];
  const float* b1   = (const float*)d_in[9];
  const float* W2   = (const float*)d_in[10];
  const float* b2   = (const float*)d_in[11];
  const float* Wih  = (const float*)d_in[12];
  const float* bih  = (const float*)d_in[13];
  const float* Whh  = (const float*)d_in[14];
  const float* bhh  = (const float*)d_in[15];
  float* out = (float*)d_out;

  const size_t gi_bytes = (size_t)B_ * T_ * GCOLS * sizeof(float);
  const int use_gi = (ws_size >= gi_bytes) ? 1 : 0;
  float* gi = (float*)d_ws;

  if (use_gi)
    gi_precompute<<<(B_ * T_) / 16, 384, 0, stream>>>(Y, Mm, Hh, Wih, bih, gi);

  odernn_kernel<<<B_, 384, 0, stream>>>(
      z0, tdyn, Y, Mm, Hh, lens, W0, b0, W1, b1, W2, b2,
      Wih, bih, Whh, bhh, use_gi ? gi : nullptr, out, use_gi);
}

// Round 3
// 12187.922 us; speedup vs baseline: 1.0804x; 1.0804x over previous
//
#include <hip/hip_runtime.h>
#include <cstdint>
#include <cstddef>

#define B_    256
#define T_    1024
#define NDYN  20
#define DH    64
#define DZ    128
#define HIDN  64
#define GCOLS 384   // 3*DZ
#define XDIM  104   // 2*NDYN + DH

// chunk-padded LDS index: 16-float chunks at stride 20 (conflict-free float4 reads)
__device__ __forceinline__ int cpad(int k) { return (k >> 4) * 20 + (k & 15); }

// DPP cross-lane add (VALU pipe, not LDS). CTRL: 0xB1=quad_perm(1,0,3,2) ~ xor1,
// 0x4E=quad_perm(2,3,0,1) ~ xor2, 0x141=row_half_mirror ~ xor4 (valid once quads uniform).
template<int CTRL, int XORMASK>
__device__ __forceinline__ float dpp_sum(float v) {
#if __has_builtin(__builtin_amdgcn_mov_dpp)
  int o = __builtin_amdgcn_mov_dpp(__float_as_int(v), CTRL, 0xF, 0xF, true);
  return v + __int_as_float(o);
#else
  return v + __shfl_xor(v, XORMASK);
#endif
}

__device__ __forceinline__ float tanh_fast(float x) {
  float a = __expf(-2.f * fabsf(x));
  return copysignf((1.f - a) / (1.f + a), x);
}
__device__ __forceinline__ float sigm(float x) { return 1.f / (1.f + __expf(-x)); }

// launch_bounds(384,1): 6-wave block, 1 wave/EU min -> 256-VGPR cap.
// (384,2) forced <=128 VGPRs (12 waves/CU = 3/EU only reachable at the 128-step)
// and spilled ~90 floats/thread of weights to scratch -> 16 GB/dispatch HBM traffic.
__global__ __launch_bounds__(384, 1) void odernn_kernel(
    const float* __restrict__ z0, const float* __restrict__ tdyn,
    const float* __restrict__ Y, const float* __restrict__ Mm,
    const float* __restrict__ Hh, const int* __restrict__ lens,
    const float* __restrict__ W0, const float* __restrict__ b0,
    const float* __restrict__ W1, const float* __restrict__ b1,
    const float* __restrict__ W2, const float* __restrict__ b2,
    const float* __restrict__ Wih, const float* __restrict__ bih,
    const float* __restrict__ Whh, const float* __restrict__ bhh,
    const float* __restrict__ gi_pre, float* __restrict__ out, int use_gi)
{
  const int tid = threadIdx.x;
  const int b   = blockIdx.x;

  __shared__ __align__(16) float vinP[160];   // RK4 input v, 8 chunks of 16 @ stride 20
  __shared__ __align__(16) float h1P[80];     // 4 chunks
  __shared__ __align__(16) float h2P[80];     // 4 chunks
  __shared__ __align__(16) float zodeL[128];  // flat, float4-broadcast in GRU
  __shared__ float zcurL[128];
  __shared__ float gateL[384];
  __shared__ float gateN[128];
  __shared__ float xsL[112];

  // Register-resident weights (all fp32):
  //   whh[128]: GRU column tid of Whh
  //   wA[32]: tid<256 -> L0 slice ; tid>=256 -> L2 slice
  //   wB[32]: tid<128 -> L1 slice ; 128<=tid<256 -> L2 slice
  float wA[32], wB[32], whh[128];

  // chunked init (4 x 32) keeps peak outstanding-load pressure moderate
  #pragma unroll
  for (int c = 0; c < 4; ++c) {
    #pragma unroll
    for (int i = 0; i < 32; ++i) {
      const int k = 32 * c + i;
      whh[k] = Whh[k * GCOLS + tid];
    }
  }

  if (tid < 256) {            // L0: jg=tid>>3 (2 outputs), p=tid&7 (K-chunk of 16)
    const int jg = tid >> 3, p = tid & 7, j0 = 2 * jg, kb = 16 * p;
    #pragma unroll
    for (int i = 0; i < 16; ++i) {
      wA[i]      = W0[(kb + i) * HIDN + j0];
      wA[16 + i] = W0[(kb + i) * HIDN + j0 + 1];
    }
  } else {                    // L2 (upper half of thread slots)
    const int u = tid - 128, jg = u >> 2, p = u & 3, j0 = 2 * jg, kb = 16 * p;
    #pragma unroll
    for (int i = 0; i < 16; ++i) {
      wA[i]      = W2[(kb + i) * DZ + j0];
      wA[16 + i] = W2[(kb + i) * DZ + j0 + 1];
    }
  }
  if (tid < 128) {            // L1: jg=tid>>2, p=tid&3
    const int jg = tid >> 2, p = tid & 3, j0 = 2 * jg, kb = 16 * p;
    #pragma unroll
    for (int i = 0; i < 16; ++i) {
      wB[i]      = W1[(kb + i) * HIDN + j0];
      wB[16 + i] = W1[(kb + i) * HIDN + j0 + 1];
    }
  } else if (tid < 256) {     // L2 (lower half of thread slots)
    const int u = tid - 128, jg = u >> 2, p = u & 3, j0 = 2 * jg, kb = 16 * p;
    #pragma unroll
    for (int i = 0; i < 16; ++i) {
      wB[i]      = W2[(kb + i) * DZ + j0];
      wB[16 + i] = W2[(kb + i) * DZ + j0 + 1];
    }
  }

  float b0r = 0.f, b1r = 0.f, b2r = 0.f;
  if (tid < 256 && (tid & 7) < 2) b0r = b0[2 * (tid >> 3) + (tid & 7)];
  if (tid < 128 && (tid & 3) < 2) b1r = b1[2 * (tid >> 2) + (tid & 3)];
  if (tid >= 128 && ((tid - 128) & 3) < 2)
    b2r = b2[2 * ((tid - 128) >> 2) + ((tid - 128) & 3)];
  const float bhhr = bhh[tid];
  const float bihr = bih[tid];
  const int   lenb = lens[b];

  if (tid < 128) {
    float zv = z0[(size_t)b * DZ + tid];
    vinP[cpad(tid)] = zv;
    zcurL[tid] = zv;
  }
  __syncthreads();

  float* Zbase = out + (size_t)B_ * DZ;
  const float* tdb = tdyn + (size_t)b * T_;

  const int u2 = tid - 128, jg2 = u2 >> 2, p2 = u2 & 3;  // L2 role (valid tid>=128)
  const int j2 = 2 * jg2 + p2;                           // L2 writer output (p2<2)

  for (int t = 0; t < T_; ++t) {
    const size_t bt = (size_t)b * T_ + t;
    // dt computed per-thread from global tdyn (no serializing LDS scalar):
    // t==0 -> dt = 0 exactly (matches reference's t_prev init = t_dyn[:,0]).
    const float dt = (t == 0) ? 0.f : fmaxf(tdb[t] - tdb[t - 1], 0.f);

    float gival = 0.f;
    if (use_gi) {
      gival = gi_pre[bt * GCOLS + tid];   // prefetch; consumed ~500 cyc later
    } else if (tid < XDIM) {
      float v;
      if (tid < 20)      v = Y[bt * NDYN + tid];
      else if (tid < 40) v = Mm[bt * NDYN + (tid - 20)];
      else               v = Hh[bt * DH + (tid - 40)];
      xsL[tid] = v;
    }

    float zreg = 0.f, kacc = 0.f;
    if (tid >= 128 && p2 < 2) zreg = zcurL[j2];

    #pragma unroll
    for (int e = 0; e < 4; ++e) {
      // ---- L0: 64 outs, K=128 ---- (threads 0..255, group of 8, 2 outs each)
      if (tid < 256) {
        const int p = tid & 7, jg = tid >> 3;
        const float4* vp = (const float4*)&vinP[p * 20];
        float a0 = 0.f, a1 = 0.f;
        #pragma unroll
        for (int q = 0; q < 4; ++q) {
          float4 v = vp[q];
          a0 += wA[4*q+0]*v.x + wA[4*q+1]*v.y + wA[4*q+2]*v.z + wA[4*q+3]*v.w;
          a1 += wA[16+4*q+0]*v.x + wA[16+4*q+1]*v.y + wA[16+4*q+2]*v.z + wA[16+4*q+3]*v.w;
        }
        a0 = dpp_sum<0xB1,1>(a0); a0 = dpp_sum<0x4E,2>(a0); a0 = dpp_sum<0x141,4>(a0);
        a1 = dpp_sum<0xB1,1>(a1); a1 = dpp_sum<0x4E,2>(a1); a1 = dpp_sum<0x141,4>(a1);
        if (p < 2)
          h1P[cpad(2 * jg + p)] = tanh_fast((p ? a1 : a0) + b0r);
      }
      __syncthreads();
      // ---- L1: 64 outs, K=64 ---- (threads 0..127, group of 4)
      if (tid < 128) {
        const int p = tid & 3, jg = tid >> 2;
        const float4* hp = (const float4*)&h1P[p * 20];
        float a0 = 0.f, a1 = 0.f;
        #pragma unroll
        for (int q = 0; q < 4; ++q) {
          float4 v = hp[q];
          a0 += wB[4*q+0]*v.x + wB[4*q+1]*v.y + wB[4*q+2]*v.z + wB[4*q+3]*v.w;
          a1 += wB[16+4*q+0]*v.x + wB[16+4*q+1]*v.y + wB[16+4*q+2]*v.z + wB[16+4*q+3]*v.w;
        }
        a0 = dpp_sum<0xB1,1>(a0); a0 = dpp_sum<0x4E,2>(a0);
        a1 = dpp_sum<0xB1,1>(a1); a1 = dpp_sum<0x4E,2>(a1);
        if (p < 2)
          h2P[cpad(2 * jg + p)] = tanh_fast((p ? a1 : a0) + b1r);
      }
      __syncthreads();
      // ---- L2: 128 outs, K=64 ---- (threads 128..383, group of 4)
      if (tid >= 128) {
        const float4* hp = (const float4*)&h2P[p2 * 20];
        float a0 = 0.f, a1 = 0.f;
        if (tid < 256) {
          #pragma unroll
          for (int q = 0; q < 4; ++q) {
            float4 v = hp[q];
            a0 += wB[4*q+0]*v.x + wB[4*q+1]*v.y + wB[4*q+2]*v.z + wB[4*q+3]*v.w;
            a1 += wB[16+4*q+0]*v.x + wB[16+4*q+1]*v.y + wB[16+4*q+2]*v.z + wB[16+4*q+3]*v.w;
          }
        } else {
          #pragma unroll
          for (int q = 0; q < 4; ++q) {
            float4 v = hp[q];
            a0 += wA[4*q+0]*v.x + wA[4*q+1]*v.y + wA[4*q+2]*v.z + wA[4*q+3]*v.w;
            a1 += wA[16+4*q+0]*v.x + wA[16+4*q+1]*v.y + wA[16+4*q+2]*v.z + wA[16+4*q+3]*v.w;
          }
        }
        a0 = dpp_sum<0xB1,1>(a0); a0 = dpp_sum<0x4E,2>(a0);
        a1 = dpp_sum<0xB1,1>(a1); a1 = dpp_sum<0x4E,2>(a1);
        if (p2 < 2) {
          const float kv = dt * ((p2 ? a1 : a0) + b2r);
          if (e == 0)      kacc = kv;
          else if (e == 3) kacc += kv;
          else             kacc += 2.f * kv;
          if (e < 3) {
            const float a = (e == 2) ? 1.f : 0.5f;
            vinP[cpad(j2)] = zreg + a * kv;
          } else {
            zodeL[j2] = zreg + kacc * (1.f / 6.f);
          }
        }
      }
      __syncthreads();
    }

    // ---- GRU: column tid ----
    {
      float gh = bhhr;
      const float4* zp = (const float4*)zodeL;
      #pragma unroll
      for (int q = 0; q < 32; ++q) {
        float4 zv = zp[q];
        gh += whh[4*q+0]*zv.x + whh[4*q+1]*zv.y + whh[4*q+2]*zv.z + whh[4*q+3]*zv.w;
      }
      float gi;
      if (use_gi) gi = gival;
      else {
        gi = bihr;
        for (int i = 0; i < XDIM; ++i) gi += xsL[i] * Wih[(size_t)i * GCOLS + tid];
      }
      if (tid < 256) gateL[tid] = gi + gh;
      else { gateL[tid] = gh; gateN[tid - 256] = gi; }
    }
    __syncthreads();

    if (tid < 128) {
      const float r  = sigm(gateL[tid]);
      const float uu = sigm(gateL[128 + tid]);
      const float n  = tanh_fast(gateN[tid] + r * gateL[256 + tid]);
      const float zo = zodeL[tid];
      const float zn = (1.f - uu) * n + uu * zo;
      const float znew = (t < lenb) ? zn : zo;
      vinP[cpad(tid)] = znew;
      zcurL[tid] = znew;
      Zbase[bt * DZ + tid] = znew;
    }
    __syncthreads();
  }

  if (tid < 128) out[(size_t)b * DZ + tid] = zcurL[tid];
}

// ---- pass 1: gi[bt][c] = b_ih[c] + x[bt] @ W_ih  (input-only, fully parallel, fp32)
__global__ __launch_bounds__(384) void gi_precompute(
    const float* __restrict__ Y, const float* __restrict__ Mm,
    const float* __restrict__ Hh, const float* __restrict__ Wih,
    const float* __restrict__ bih, float* __restrict__ gi)
{
  __shared__ float Xs[XDIM][16];
  const int tid = threadIdx.x;
  const size_t bt0 = (size_t)blockIdx.x * 16;
  for (int idx = tid; idx < XDIM * 16; idx += 384) {
    int r = idx & 15, c = idx >> 4;
    size_t bt = bt0 + r;
    float v;
    if (c < 20)      v = Y[bt * NDYN + c];
    else if (c < 40) v = Mm[bt * NDYN + (c - 20)];
    else             v = Hh[bt * DH + (c - 40)];
    Xs[c][r] = v;
  }
  __syncthreads();
  float acc[16];
  const float bv = bih[tid];
  #pragma unroll
  for (int r = 0; r < 16; ++r) acc[r] = bv;
  for (int i = 0; i < XDIM; ++i) {
    float w = Wih[i * GCOLS + tid];
    const float4* xp = (const float4*)(&Xs[i][0]);
    #pragma unroll
    for (int q = 0; q < 4; ++q) {
      float4 xv = xp[q];
      acc[4*q + 0] += xv.x * w;
      acc[4*q + 1] += xv.y * w;
      acc[4*q + 2] += xv.z * w;
      acc[4*q + 3] += xv.w * w;
    }
  }
  #pragma unroll
  for (int r = 0; r < 16; ++r) gi[(bt0 + r) * GCOLS + tid] = acc[r];
}

extern "C" void kernel_launch(void* const* d_in, const int* in_sizes, int n_in,
                              void* d_out, int out_size, void* d_ws, size_t ws_size,
                              hipStream_t stream) {
  const float* z0   = (const float*)d_in[0];
  const float* tdyn = (const float*)d_in[1];
  const float* Y    = (const float*)d_in[2];
  const float* Mm   = (const float*)d_in[3];
  const float* Hh   = (const float*)d_in[4];
  const int*   lens = (const int*)d_in[5];
  const float* W0   = (const float*)d_in[6];
  const float* b0   = (const float*)d_in[7];
  const float* W1   = (const float*)d_in[8];
  const float* b1   = (const float*)d_in[9];
  const float* W2   = (const float*)d_in[10];
  const float* b2   = (const float*)d_in[11];
  const float* Wih  = (const float*)d_in[12];
  const float* bih  = (const float*)d_in[13];
  const float* Whh  = (const float*)d_in[14];
  const float* bhh  = (const float*)d_in[15];
  float* out = (float*)d_out;

  const size_t gi_bytes = (size_t)B_ * T_ * GCOLS * sizeof(float);
  const int use_gi = (ws_size >= gi_bytes) ? 1 : 0;
  float* gi = (float*)d_ws;

  if (use_gi)
    gi_precompute<<<(B_ * T_) / 16, 384, 0, stream>>>(Y, Mm, Hh, Wih, bih, gi);

  odernn_kernel<<<B_, 384, 0, stream>>>(
      z0, tdyn, Y, Mm, Hh, lens, W0, b0, W1, b1, W2, b2,
      Wih, bih, Whh, bhh, use_gi ? gi : nullptr, out, use_gi);
}